// Round 12
// baseline (45.603 us; speedup 1.0000x reference)
//
#include <hip/hip_runtime.h>
#include <math.h>

// Problem constants: B=4, C=128, H=W=96, E=4, C8=16, scale=2 (baked in)
#define Bn 4
#define Cc 128
#define Hh 96
#define Ww 96
#define H2c 192
#define W2c 192
#define HW (Hh*Ww)
#define HW2 (H2c*W2c)

// Workspace layout:
//   floats: [WC_OFF,+4*2048) Wc_t[cls][c][o] ; [WE_OFF,+4*2048) We[cls][c][o]
//           [TAP_OFF,+16) per-class {tx,ty,Dx,Dy}
//   ushort (bf16) at float-offset M_OFF: M[cls][c_out][128]  (folded We*Wc+I)
#define WC_OFF 0
#define WE_OFF (4*2048)
#define TAP_OFF (8*2048)
#define M_OFF  16640          // float offset; byte 66560 (16B aligned)

typedef float  f32x4  __attribute__((ext_vector_type(4)));
typedef short  s16x8  __attribute__((ext_vector_type(8)));

__device__ __forceinline__ unsigned f2bf(float f) {
    unsigned u = __float_as_uint(f);
    return (u + 0x7FFFu + ((u >> 16) & 1u)) >> 16;   // RNE to bf16
}

// global -> LDS DMA, 16B per lane. LDS dest = wave-uniform base + lane*16.
__device__ __forceinline__ void gload_lds16(const float* g, float* l) {
    __builtin_amdgcn_global_load_lds(
        (const __attribute__((address_space(1))) unsigned int*)g,
        (__attribute__((address_space(3))) unsigned int*)l,
        16, 0, 0);
}

// ---------------------------------------------------------------------------
// K1: per-class tiny MLP -> routing/offsets; mix expert weights; tap constants.
__global__ __launch_bounds__(256) void k1_mix(
    const float* __restrict__ wcomp, const float* __restrict__ wexp,
    const float* __restrict__ bw1, const float* __restrict__ bb1,
    const float* __restrict__ bw2, const float* __restrict__ bb2,
    const float* __restrict__ rw,  const float* __restrict__ rb,
    const float* __restrict__ ow,  const float* __restrict__ ob,
    float* __restrict__ ws)
{
    __shared__ float e1[64], e2[64], rr[4], of[2];
    const int tid   = threadIdx.x;
    const int cls   = blockIdx.x >> 4;
    const int chunk = blockIdx.x & 15;
    const float chv = (cls & 2) ? 0.25f : -0.25f;
    const float cwv = (cls & 1) ? 0.25f : -0.25f;

    if (tid < 64) {
        float h = bw1[tid*3+0]*0.5f + bw1[tid*3+1]*chv + bw1[tid*3+2]*cwv + bb1[tid];
        e1[tid] = fmaxf(h, 0.f);
    }
    __syncthreads();
    if (tid < 64) {
        float s = bb2[tid];
        for (int i = 0; i < 64; ++i) s += bw2[tid*64+i]*e1[i];
        e2[tid] = fmaxf(s, 0.f);
    }
    __syncthreads();
    if (tid < 6) {
        if (tid < 4) {
            float s = rb[tid];
            for (int i = 0; i < 64; ++i) s += rw[tid*64+i]*e2[i];
            rr[tid] = 1.f/(1.f+expf(-s));
        } else {
            const int d = tid - 4;
            float s = ob[d];
            for (int i = 0; i < 64; ++i) s += ow[d*64+i]*e2[i];
            of[d] = s;
        }
    }
    __syncthreads();
    const float r0 = rr[0], r1 = rr[1], r2 = rr[2], r3 = rr[3];

    if (tid < 128) {
        const int idx = chunk*128 + tid;
        const int o = idx >> 7, c = idx & 127;
        const float v = r0*wcomp[idx] + r1*wcomp[2048+idx]
                      + r2*wcomp[4096+idx] + r3*wcomp[6144+idx];
        ws[WC_OFF + cls*2048 + c*16 + o] = v;     // transposed [c][o]
    } else {
        const int idx = chunk*128 + (tid - 128);
        ws[WE_OFF + cls*2048 + idx] =             // native [c][o]
            r0*wexp[idx] + r1*wexp[2048+idx] + r2*wexp[4096+idx] + r3*wexp[6144+idx];
    }
    if (chunk == 0 && tid == 0) {
        const float fx = cwv + of[0];
        const float fy = chv + of[1];
        const float Dx = floorf(fx), Dy = floorf(fy);
        ws[TAP_OFF + cls*4 + 0] = fx - Dx;
        ws[TAP_OFF + cls*4 + 1] = fy - Dy;
        ws[TAP_OFF + cls*4 + 2] = Dx;
        ws[TAP_OFF + cls*4 + 3] = Dy;
    }
}

// ---------------------------------------------------------------------------
// K1b: fold M[cls] = We_mix * Wc_mix + I, store bf16 row-major [c_out][c_in].
__global__ __launch_bounds__(256) void k1b_fold(
    const float* __restrict__ wsr, unsigned short* __restrict__ Mw)
{
    const int t   = blockIdx.x*256 + threadIdx.x;    // 0..16383
    const int cls = t >> 12;
    const int rem = t & 4095;
    const int co  = rem >> 5;            // c_out 0..127
    const int ci0 = (rem & 31) * 4;      // c_in base
    const float* we = wsr + WE_OFF + cls*2048 + co*16;

    float m[4];
    #pragma unroll
    for (int q = 0; q < 4; ++q) {
        const float* wc = wsr + WC_OFF + cls*2048 + (ci0+q)*16;
        float s = 0.f;
        #pragma unroll
        for (int o = 0; o < 16; ++o) s += we[o]*wc[o];
        if (co == ci0 + q) s += 1.f;     // residual identity folded in
        m[q] = s;
    }
    uint2 v;
    v.x = f2bf(m[0]) | (f2bf(m[1]) << 16);
    v.y = f2bf(m[2]) | (f2bf(m[3]) << 16);
    *reinterpret_cast<uint2*>(Mw + (size_t)cls*16384 + co*128 + ci0) = v;
}

// Edge remap (verified rounds 1-11).
__device__ __forceinline__ void remap_axis(int c0, int last, float w0, float w1,
                                           int& base, float& a0, float& a1)
{
    base = min(max(c0, 0), last - 1);
    if (c0 >= 0 && c0 < last) { a0 = w0;  a1 = w1;  }
    else if (c0 == -1)        { a0 = w1;  a1 = 0.f; }
    else if (c0 == last)      { a0 = 0.f; a1 = w0;  }
    else                      { a0 = 0.f; a1 = 0.f; }
}

// ---------------------------------------------------------------------------
// K2: pipelined wave-cooperative window staging + MFMA GEMM.
// Identical math/layout to round 11; staging restructured into 8 chunks of
// 4 channels, double-buffered (2 x 2KB per wave), counted vmcnt(2) so 2
// chunks stay in flight (T4: never drain mid-loop). LDS = 32 KB total ->
// 5 blocks/CU (20 waves) vs round 11's 3.
__global__ __launch_bounds__(256) void k2_mfma(
    const float* __restrict__ x, const float* __restrict__ wsr,
    const unsigned short* __restrict__ Mw, float* __restrict__ out)
{
    __shared__ __align__(16) unsigned short lF[64*128];   // 16 KB fea tile (swizzled)
    __shared__ __align__(16) float lWin[4*2*512];         // 16 KB: [wave][buf][512]

    const int tid = threadIdx.x;
    const int xl  = tid & 63;
    const int grp = tid >> 6;

    // XCD-paired swizzle: 2304 = 8 XCDs * 288; 4 classes of a tile consecutive
    // on one XCD (stride-2 stores merge in L2, x rows shared).
    const int n = blockIdx.x;
    const int w = (n & 7)*288 + (n >> 3);
    const int cls  = w & 3;
    const int px_  = cls & 1, py = (cls >> 1) & 1;
    const int rest = w >> 2;           // 0..575
    const int tile = rest % 144;
    const int b    = rest / 144;
    const int jt = tile/3, xs = tile - jt*3;
    const int j0 = jt*2, i0 = xs*32;   // class-tile origin (half-res)

    // ---- A fragments: M rows for this wave's 32 out-channels (L2-hot) ----
    const unsigned short* Mc = Mw + (size_t)cls*16384;
    const int lo = xl & 15, hi = xl >> 4;
    s16x8 a[2][4];
    #pragma unroll
    for (int t = 0; t < 2; ++t)
        #pragma unroll
        for (int kk = 0; kk < 4; ++kk)
            a[t][kk] = *reinterpret_cast<const s16x8*>(
                Mc + (32*grp + 16*t + lo)*128 + kk*32 + hi*8);

    // ---- per-pixel tap constants (lane = pixel slot: pr = s>>5, pc = s&31) ----
    const int pr = xl >> 5, pc = xl & 31;
    const int j = j0 + pr, i = i0 + pc;

    const float tx = wsr[TAP_OFF + cls*4 + 0];
    const float ty = wsr[TAP_OFF + cls*4 + 1];
    const int   Dx = (int)wsr[TAP_OFF + cls*4 + 2];
    const int   Dy = (int)wsr[TAP_OFF + cls*4 + 3];
    int basex, basey; float ax0, ax1, ay0, ay1;
    remap_axis(i + Dx, Ww - 1, 1.f - tx, tx, basex, ax0, ax1);
    remap_axis(j + Dy, Hh - 1, 1.f - ty, ty, basey, ay0, ay1);
    const float w00 = ay0*ax0, w01 = ay0*ax1, w10 = ay1*ax0, w11 = ay1*ax1;

    // window geometry (verified r11): rows clamp(jD+r) r=0..2, cols cs0..cs0+39
    const int c0  = i0 + Dx;
    const int cs0 = min(max(0, c0 & ~3), Ww - 40);
    const int cidx = basex - cs0;
    const int ro0 = pr*40 + cidx;
    const int ro1 = ro0 + 40;

    // staging lane assignment (verified r11): half-wave sl loads float4
    // (row lr, quad lq) of channel (pair base + xl>>5); lanes 30,31 duplicate.
    const int jD = j0 + Dy;
    const int sl = xl & 31;
    const int s2 = min(sl, 29);
    const int lr = s2 / 10, lq = s2 - lr*10;
    const int lrow = min(max(jD + lr, 0), Hh - 1);
    const float* gsrc = x + (size_t)b*Cc*HW + (size_t)lrow*Ww + cs0 + 4*lq;
    const int chsub = xl >> 5;         // 0 or 1 within a pair

    float* winw = lWin + grp*1024;     // this wave's 2 x 512-float buffers

#define ISSUE(q) { \
    _Pragma("unroll") \
    for (int p = 0; p < 2; ++p) \
        gload_lds16(gsrc + (size_t)(grp*32 + (q)*4 + p*2 + chsub)*HW, \
                    winw + ((q)&1)*512 + p*256); }

    // ---- 8-chunk pipeline, 2 chunks in flight, counted vmcnt ----
    ISSUE(0)
    ISSUE(1)
    #pragma unroll
    for (int q = 0; q < 8; ++q) {
        if (q < 7) asm volatile("s_waitcnt vmcnt(2)" ::: "memory");
        else       asm volatile("s_waitcnt vmcnt(0)" ::: "memory");
        __builtin_amdgcn_sched_barrier(0);
        // consume chunk q: 4 channels' fea + bf16 pack into lF
        {
            const float* wb = winw + (q&1)*512;
            float f[4];
            #pragma unroll
            for (int u = 0; u < 4; ++u) {
                const float* wc = wb + (u>>1)*256 + (u&1)*128;
                f[u] = w00*wc[ro0] + w01*wc[ro0+1] + w10*wc[ro1] + w11*wc[ro1+1];
            }
            uint2 v;
            v.x = f2bf(f[0]) | (f2bf(f[1]) << 16);
            v.y = f2bf(f[2]) | (f2bf(f[3]) << 16);
            const int c = grp*32 + q*4;
            int byte = xl*256 + c*2;
            byte ^= (xl & 7) << 4;
            *reinterpret_cast<uint2*>(reinterpret_cast<char*>(lF) + byte) = v;
        }
        if (q < 6) {
            // WAR fence: chunk q's LDS reads retired before DMA re-fills buf
            asm volatile("s_waitcnt lgkmcnt(0)" ::: "memory");
            __builtin_amdgcn_sched_barrier(0);
            ISSUE(q+2)
        }
    }
#undef ISSUE
    __syncthreads();

    // ---- GEMM: D[128ch x 64px] = M @ fea (residual folded into M) ----
    f32x4 acc[2][4];
    #pragma unroll
    for (int t = 0; t < 2; ++t)
        #pragma unroll
        for (int nn = 0; nn < 4; ++nn) acc[t][nn] = (f32x4){0.f, 0.f, 0.f, 0.f};

    #pragma unroll
    for (int kk = 0; kk < 4; ++kk) {
        #pragma unroll
        for (int nn = 0; nn < 4; ++nn) {
            int byte = (nn*16 + lo)*256 + kk*64 + hi*16;
            byte ^= (lo & 7) << 4;
            const s16x8 bf = *reinterpret_cast<const s16x8*>(
                reinterpret_cast<const char*>(lF) + byte);
            acc[0][nn] = __builtin_amdgcn_mfma_f32_16x16x32_bf16(a[0][kk], bf, acc[0][nn], 0, 0, 0);
            acc[1][nn] = __builtin_amdgcn_mfma_f32_16x16x32_bf16(a[1][kk], bf, acc[1][nn], 0, 0, 0);
        }
    }

    // ---- store (r7/r11 pattern: stride-2 merge with partner class) ----
    #pragma unroll
    for (int t = 0; t < 2; ++t)
        #pragma unroll
        for (int nn = 0; nn < 4; ++nn) {
            const int slot2 = nn*16 + lo;
            const int pr2 = slot2 >> 5, pc2 = slot2 & 31;
            const int yg = 2*(j0 + pr2) + py;
            const int xg = 2*(i0 + pc2) + px_;
            const int ch0 = 32*grp + 16*t + hi*4;
            float* op = out + ((size_t)(b*Cc + ch0)*H2c + yg)*W2c + xg;
            #pragma unroll
            for (int r = 0; r < 4; ++r)
                op[(size_t)r*HW2] = acc[t][nn][r];
        }
}

extern "C" void kernel_launch(void* const* d_in, const int* in_sizes, int n_in,
                              void* d_out, int out_size, void* d_ws, size_t ws_size,
                              hipStream_t stream) {
    const float* x     = (const float*)d_in[0];
    const float* wcomp = (const float*)d_in[1];
    const float* wexp  = (const float*)d_in[2];
    const float* bw1   = (const float*)d_in[3];
    const float* bb1   = (const float*)d_in[4];
    const float* bw2   = (const float*)d_in[5];
    const float* bb2   = (const float*)d_in[6];
    const float* rw    = (const float*)d_in[7];
    const float* rb    = (const float*)d_in[8];
    const float* ow    = (const float*)d_in[9];
    const float* ob    = (const float*)d_in[10];
    float* out = (float*)d_out;
    float* ws  = (float*)d_ws;
    unsigned short* Mw = (unsigned short*)(ws + M_OFF);   // ~194 KB total used

    k1_mix<<<64, 256, 0, stream>>>(wcomp, wexp, bw1, bb1, bw2, bb2, rw, rb, ow, ob, ws);
    k1b_fold<<<64, 256, 0, stream>>>(ws, Mw);
    k2_mfma<<<2304, 256, 0, stream>>>(x, ws, Mw, out);
}